// Round 1
// baseline (20043.533 us; speedup 1.0000x reference)
//
#include <hip/hip_runtime.h>
#include <math.h>

// CustomRNN: B=64,S=512,I=256,H=512,O=256,L=2  (all fp32)
// Plan:
//  K1 fold:  W0 = W_in@W_i2h[0]  (256x512), b0 = b_in@W_i2h[0]+b_i2h[0]+b_h2h[0]
//  K2 seq :  persistent 256-WG cooperative kernel, 513 ticks, 1 grid barrier/tick.
//            WGs 0..127: layer0  h0(t)=tanh(x_t@W0 + h0(t-1)@Wh0 + b0)
//            WGs 128..255: layer1 h1(t)=tanh(h0(t)@Wi1 + h1(t-1)@Wh1 + b1), t=tick-1
//            weight slices live in LDS for all 512 steps.
//  K3 out :  out = H1_all @ W_out + b_out   (batched GEMM over all 32768 rows)
//  K4 tail:  final hidden states -> d_out tail
//
// ws layout (floats): W0[256*512] | b0[512] | h0_buf[2*64*512] | H1[512*64*512] | barrier(u32[2])
// total ~68 MB.

constexpr int BB = 64;
constexpr int SS = 512;
constexpr int II = 256;
constexpr int HH = 512;
constexpr int OO = 256;

// ---------------- K1: fold input weights ----------------
__global__ __launch_bounds__(256) void fold_k(
    const float* __restrict__ Win, const float* __restrict__ bin,
    const float* __restrict__ Wi2h, const float* __restrict__ bi2h,
    const float* __restrict__ bh2h,
    float* __restrict__ W0, float* __restrict__ b0)
{
    int gid = blockIdx.x * 256 + threadIdx.x;
    const float* Wi0 = Wi2h;  // layer 0 slice [HH][HH]
    if (gid < II * HH) {
        int i = gid / HH, j = gid % HH;
        float acc = 0.f;
        for (int k = 0; k < HH; ++k)
            acc = fmaf(Win[i * HH + k], Wi0[k * HH + j], acc);
        W0[gid] = acc;
    } else if (gid < II * HH + HH) {
        int j = gid - II * HH;
        float acc = bi2h[j] + bh2h[j];   // layer-0 biases folded
        for (int k = 0; k < HH; ++k)
            acc = fmaf(bin[k], Wi0[k * HH + j], acc);
        b0[j] = acc;
    }
}

// ---------------- K2: persistent sequential kernel ----------------
// grid = 256 WGs x 256 thr. 1 WG/CU -> co-residency guaranteed.
// tile: 32 rows x 8 cols per WG; thread = (m = tid>>3, n = tid&7).
// LDS: two transposed weight slices [8][516] (stride 516 floats -> conflict-free b128).

__device__ __forceinline__ void grid_bar(unsigned* cnt, unsigned target)
{
    __syncthreads();
    if (threadIdx.x == 0) {
        __threadfence();  // release my tile's global writes (agent scope)
        __hip_atomic_fetch_add(cnt, 1u, __ATOMIC_ACQ_REL, __HIP_MEMORY_SCOPE_AGENT);
        while (__hip_atomic_load(cnt, __ATOMIC_ACQUIRE, __HIP_MEMORY_SCOPE_AGENT) < target) {
            __builtin_amdgcn_s_sleep(2);
        }
    }
    __syncthreads();
}

__global__ __launch_bounds__(256) void rnn_seq(
    const float* __restrict__ x, const float* __restrict__ hprev,
    const float* __restrict__ Wi2h, const float* __restrict__ bi2h,
    const float* __restrict__ Wh2h, const float* __restrict__ bh2h,
    const float* __restrict__ W0, const float* __restrict__ b0,
    float* __restrict__ h0buf, float* __restrict__ H1,
    unsigned* bar_cnt)
{
    __shared__ float lds[2 * 8 * 516];   // 33 KB
    float* wA = lds;                     // layer0: Wh0 slice | layer1: Wh1 slice (K=512)
    float* wB = lds + 8 * 516;           // layer0: W0 slice (K=256) | layer1: Wi1 slice (K=512)

    const int tid = threadIdx.x;
    const int wg  = blockIdx.x;
    const int layer = wg >> 7;           // 0..1
    const int id  = wg & 127;
    const int mb  = id >> 6;             // 0..1   (m0 = mb*32)
    const int nb  = id & 63;             // 0..63  (n0 = nb*8)
    const int m   = tid >> 3;            // 0..31
    const int n   = tid & 7;             // 0..7
    const int row = mb * 32 + m;         // batch row 0..63
    const int col = nb * 8 + n;          // hidden col 0..511

    // --- load weight slices into LDS (transposed), once ---
    if (layer == 0) {
        const float* Wh0 = Wh2h;                         // layer 0
        for (int idx = tid; idx < HH * 8; idx += 256) {
            int k = idx >> 3, nn = idx & 7;
            wA[nn * 516 + k] = Wh0[k * HH + nb * 8 + nn];
        }
        for (int idx = tid; idx < II * 8; idx += 256) {
            int k = idx >> 3, nn = idx & 7;
            wB[nn * 516 + k] = W0[k * HH + nb * 8 + nn];
        }
    } else {
        const float* Wi1 = Wi2h + HH * HH;
        const float* Wh1 = Wh2h + HH * HH;
        for (int idx = tid; idx < HH * 8; idx += 256) {
            int k = idx >> 3, nn = idx & 7;
            wA[nn * 516 + k] = Wh1[k * HH + nb * 8 + nn];
            wB[nn * 516 + k] = Wi1[k * HH + nb * 8 + nn];
        }
    }
    __syncthreads();

    float bias;
    if (layer == 0) bias = b0[col];                         // all layer-0 biases folded
    else            bias = bi2h[HH + col] + bh2h[HH + col]; // layer-1 biases

    const float* wAn = wA + n * 516;
    const float* wBn = wB + n * 516;

    for (int tk = 0; tk <= SS; ++tk) {
        if (layer == 0) {
            if (tk < SS) {
                const float* h0p = (tk == 0) ? (hprev + row * HH)
                                             : (h0buf + ((tk - 1) & 1) * (BB * HH) + row * HH);
                const float* xr = x + (row * SS + tk) * II;
                float a0 = 0.f, a1 = 0.f, a2 = 0.f, a3 = 0.f;
                const float4* h4p = (const float4*)h0p;
                const float4* x4p = (const float4*)xr;
                #pragma unroll 4
                for (int kk = 0; kk < HH / 4; ++kk) {
                    float4 h4 = h4p[kk];
                    float4 w4 = *(const float4*)(wAn + 4 * kk);
                    a0 = fmaf(h4.x, w4.x, a0); a1 = fmaf(h4.y, w4.y, a1);
                    a2 = fmaf(h4.z, w4.z, a2); a3 = fmaf(h4.w, w4.w, a3);
                }
                #pragma unroll 4
                for (int kk = 0; kk < II / 4; ++kk) {
                    float4 x4 = x4p[kk];
                    float4 w4 = *(const float4*)(wBn + 4 * kk);
                    a0 = fmaf(x4.x, w4.x, a0); a1 = fmaf(x4.y, w4.y, a1);
                    a2 = fmaf(x4.z, w4.z, a2); a3 = fmaf(x4.w, w4.w, a3);
                }
                float v = (a0 + a1) + (a2 + a3) + bias;
                h0buf[(tk & 1) * (BB * HH) + row * HH + col] = tanhf(v);
            }
        } else {
            if (tk >= 1) {
                const int t = tk - 1;
                const float* h0t = h0buf + ((tk - 1) & 1) * (BB * HH) + row * HH;
                const float* h1p = (t == 0) ? (hprev + BB * HH + row * HH)
                                            : (H1 + (size_t)(t - 1) * (BB * HH) + row * HH);
                float a0 = 0.f, a1 = 0.f, a2 = 0.f, a3 = 0.f;
                const float4* h04 = (const float4*)h0t;
                const float4* h14 = (const float4*)h1p;
                #pragma unroll 4
                for (int kk = 0; kk < HH / 4; ++kk) {
                    float4 h4 = h04[kk];
                    float4 w4 = *(const float4*)(wBn + 4 * kk);   // Wi1
                    a0 = fmaf(h4.x, w4.x, a0); a1 = fmaf(h4.y, w4.y, a1);
                    a2 = fmaf(h4.z, w4.z, a2); a3 = fmaf(h4.w, w4.w, a3);
                }
                #pragma unroll 4
                for (int kk = 0; kk < HH / 4; ++kk) {
                    float4 h4 = h14[kk];
                    float4 w4 = *(const float4*)(wAn + 4 * kk);   // Wh1
                    a0 = fmaf(h4.x, w4.x, a0); a1 = fmaf(h4.y, w4.y, a1);
                    a2 = fmaf(h4.z, w4.z, a2); a3 = fmaf(h4.w, w4.w, a3);
                }
                float v = (a0 + a1) + (a2 + a3) + bias;
                H1[(size_t)t * (BB * HH) + row * HH + col] = tanhf(v);
            }
        }
        grid_bar(bar_cnt, 256u * (unsigned)(tk + 1));
    }
}

// ---------------- K3: output GEMM  out[b][s][:] = H1[s][b][:] @ Wout + bout ----------------
__global__ __launch_bounds__(256) void out_k(
    const float* __restrict__ H1, const float* __restrict__ Wout,
    const float* __restrict__ bout, float* __restrict__ out)
{
    __shared__ float wchunk[32 * 256];  // 32 KB
    __shared__ float htile[16 * 32];    // 2 KB
    const int tid = threadIdx.x;        // col 0..255
    const int r0 = blockIdx.x * 16;     // row block (row r = s*64 + b)

    float acc[16];
    #pragma unroll
    for (int mm = 0; mm < 16; ++mm) acc[mm] = 0.f;

    for (int kc = 0; kc < HH; kc += 32) {
        for (int idx = tid; idx < 32 * 256; idx += 256)
            wchunk[idx] = Wout[(kc + (idx >> 8)) * OO + (idx & 255)];
        for (int idx = tid; idx < 16 * 32; idx += 256) {
            int mm = idx >> 5, kk = idx & 31;
            htile[idx] = H1[(size_t)(r0 + mm) * HH + kc + kk];
        }
        __syncthreads();
        for (int kk = 0; kk < 32; ++kk) {
            float w = wchunk[kk * 256 + tid];
            #pragma unroll
            for (int mm = 0; mm < 16; ++mm)
                acc[mm] = fmaf(htile[mm * 32 + kk], w, acc[mm]);
        }
        __syncthreads();
    }
    float bo = bout[tid];
    #pragma unroll
    for (int mm = 0; mm < 16; ++mm) {
        int r = r0 + mm;
        int s = r >> 6, b = r & 63;
        out[((size_t)b * SS + s) * OO + tid] = acc[mm] + bo;
    }
}

// ---------------- K4: final hidden states ----------------
__global__ __launch_bounds__(256) void tail_k(
    const float* __restrict__ h0buf, const float* __restrict__ H1,
    float* __restrict__ out_tail)
{
    int gid = blockIdx.x * 256 + threadIdx.x;   // 0..2*BB*HH-1
    if (gid < BB * HH)
        out_tail[gid] = h0buf[((SS - 1) & 1) * (BB * HH) + gid];
    else if (gid < 2 * BB * HH)
        out_tail[gid] = H1[(size_t)(SS - 1) * (BB * HH) + (gid - BB * HH)];
}

// ---------------- launch ----------------
extern "C" void kernel_launch(void* const* d_in, const int* in_sizes, int n_in,
                              void* d_out, int out_size, void* d_ws, size_t ws_size,
                              hipStream_t stream)
{
    const float* x     = (const float*)d_in[0];
    const float* hprev = (const float*)d_in[1];
    const float* Win   = (const float*)d_in[2];
    const float* bin   = (const float*)d_in[3];
    const float* Wi2h  = (const float*)d_in[4];
    const float* bi2h  = (const float*)d_in[5];
    const float* Wh2h  = (const float*)d_in[6];
    const float* bh2h  = (const float*)d_in[7];
    const float* Wout  = (const float*)d_in[8];
    const float* bout  = (const float*)d_in[9];

    float* ws    = (float*)d_ws;
    float* W0    = ws;
    float* b0    = W0 + (size_t)II * HH;
    float* h0buf = b0 + HH;
    float* H1    = h0buf + 2 * BB * HH;
    unsigned* bar = (unsigned*)(H1 + (size_t)SS * BB * HH);
    float* out   = (float*)d_out;

    hipMemsetAsync(bar, 0, 2 * sizeof(unsigned), stream);
    fold_k<<<dim3((II * HH + HH + 255) / 256), dim3(256), 0, stream>>>(
        Win, bin, Wi2h, bi2h, bh2h, W0, b0);
    rnn_seq<<<dim3(256), dim3(256), 0, stream>>>(
        x, hprev, Wi2h, bi2h, Wh2h, bh2h, W0, b0, h0buf, H1, bar);
    out_k<<<dim3((BB * SS) / 16), dim3(256), 0, stream>>>(H1, Wout, bout, out);
    tail_k<<<dim3((2 * BB * HH) / 256), dim3(256), 0, stream>>>(
        h0buf, H1, out + (size_t)BB * SS * OO);
}

// Round 2
// 9562.194 us; speedup vs baseline: 2.0961x; 2.0961x over previous
//
#include <hip/hip_runtime.h>
#include <math.h>

// CustomRNN: B=64,S=512,I=256,H=512,O=256,L=2 (fp32)
// R2 design:
//  - fold:  W0 = W_in@Wi0, b0 = b_in@Wi0 + bi0 + bh0  (layer-0 input path folded)
//  - rnn_seq2: persistent 256-WG kernel, NO grid barrier, NO cache-wide fences.
//      L0 WGs (0..127):  h0(t) = tanh(h0(t-1)@Wh0 + x_t@W0 + b0)
//      L1 WGs (128..255):h1(t) = tanh(h0(t)@Wi1 + h1(t-1)@Wh1 + b1)
//      Cross-WG h exchange via device-scope (agent, relaxed) atomic u64 load/store
//      -> sc1 accesses at the coherence point (MALL); L1/L2 never invalidated,
//      so x + weights stay hot in normal caches.
//      Sync: per-row-group monotonic counters, depth-4 ring for h0.
//      Per WG: 16 rows x 16 cols; weights resident in LDS all 512 ticks;
//      h staged to LDS each tick; thread=(r, cq, kq): 4 cols x K/4 slice,
//      shfl_xor(1,2) reduces over kq.
//  - out_k: out = H1_all @ W_out + b_out ; tail_k: final hidden states.

constexpr int BB = 64;
constexpr int SS = 512;
constexpr int II = 256;
constexpr int HH = 512;
constexpr int OO = 256;

#define SCOPE_AGENT __HIP_MEMORY_SCOPE_AGENT

__device__ __forceinline__ unsigned ld_flag(const unsigned* p) {
    return __hip_atomic_load((unsigned*)p, __ATOMIC_RELAXED, SCOPE_AGENT);
}
__device__ __forceinline__ void add_flag(unsigned* p) {
    __hip_atomic_fetch_add(p, 1u, __ATOMIC_RELAXED, SCOPE_AGENT);
}
__device__ __forceinline__ void wait_ge(const unsigned* p, unsigned target) {
    while (ld_flag(p) < target) __builtin_amdgcn_s_sleep(1);
}

union F2U { float2 f; unsigned long long u; };
__device__ __forceinline__ float2 ld_coh2(const float* p) {
    F2U x;
    x.u = __hip_atomic_load((unsigned long long*)p, __ATOMIC_RELAXED, SCOPE_AGENT);
    return x.f;
}
__device__ __forceinline__ void st_coh2(float* p, float a, float b) {
    F2U x; x.f = make_float2(a, b);
    __hip_atomic_store((unsigned long long*)p, x.u, __ATOMIC_RELAXED, SCOPE_AGENT);
}

// ---------------- fold: W0 = Win@Wi0, b0 = bin@Wi0 + bi0 + bh0 ----------------
__global__ __launch_bounds__(256) void fold_k(
    const float* __restrict__ Win, const float* __restrict__ bin,
    const float* __restrict__ Wi2h, const float* __restrict__ bi2h,
    const float* __restrict__ bh2h,
    float* __restrict__ W0, float* __restrict__ b0)
{
    int gid = blockIdx.x * 256 + threadIdx.x;
    const float* Wi0 = Wi2h;
    if (gid < II * HH) {
        int i = gid / HH, j = gid % HH;
        float acc = 0.f;
        for (int k = 0; k < HH; ++k)
            acc = fmaf(Win[i * HH + k], Wi0[k * HH + j], acc);
        W0[gid] = acc;
    } else if (gid < II * HH + HH) {
        int j = gid - II * HH;
        float acc = bi2h[j] + bh2h[j];
        for (int k = 0; k < HH; ++k)
            acc = fmaf(bin[k], Wi0[k * HH + j], acc);
        b0[j] = acc;
    }
}

// ---------------- persistent sequential kernel ----------------
// LDS layout (dynamic): wB[16][STR] | hAB[16][STR]
//   L0: STR=776,  K=768  (k<512: Wh0/h0(t-1); k>=512: W0/x_t)
//   L1: STR=1036, K=1024 (k<512: Wi1/h0(t);   k>=512: Wh1/h1(t-1))
// LDS address map: adr(k) = k + 4*(k>>8)  (4-float gap per 256-block: kq lanes
// land in distinct banks; float4 never straddles a gap).

__global__ __launch_bounds__(256, 1) void rnn_seq2(
    const float* __restrict__ x, const float* __restrict__ hprev,
    const float* __restrict__ Wi2h, const float* __restrict__ bi2h,
    const float* __restrict__ Wh2h, const float* __restrict__ bh2h,
    const float* __restrict__ W0, const float* __restrict__ b0,
    float* __restrict__ ring, float* __restrict__ H1,
    unsigned* __restrict__ c0, unsigned* __restrict__ c1)
{
    extern __shared__ float lds[];
    const int tid = threadIdx.x;
    const int wg  = blockIdx.x;
    const int layer = wg >> 7;
    const int id  = wg & 127;
    const int rg  = id >> 5;          // 0..3  (16 rows each)
    const int cg  = id & 31;          // 0..31 (16 cols each)
    const int r   = tid >> 4;         // 0..15
    const int cq  = (tid >> 2) & 3;   // 0..3
    const int kq  = tid & 3;          // 0..3
    const int row0 = rg * 16;
    const int col0 = cg * 16 + cq * 4;

    const int STR = layer ? 1036 : 776;
    const int K   = layer ? 1024 : 768;
    float* wB  = lds;
    float* hAB = lds + 16 * STR;

    // ---- stage weight slice (once) ----
    for (int i = tid; i < 16 * K; i += 256) {
        int c = i & 15, k = i >> 4;
        int col = cg * 16 + c;
        float w;
        if (layer == 0) w = (k < 512) ? Wh2h[k * HH + col] : W0[(k - 512) * HH + col];
        else            w = (k < 512) ? Wi2h[HH * HH + k * HH + col]
                                      : Wh2h[HH * HH + (k - 512) * HH + col];
        wB[c * STR + k + 4 * (k >> 8)] = w;
    }

    float4 bias4;
    if (layer == 0) {
        bias4 = *(const float4*)(b0 + col0);
    } else {
        bias4 = *(const float4*)(bi2h + HH + col0);
        float4 b2 = *(const float4*)(bh2h + HH + col0);
        bias4.x += b2.x; bias4.y += b2.y; bias4.z += b2.z; bias4.w += b2.w;
    }

    const float* hp  = hAB + r * STR;
    const float* wp0 = wB + (cq * 4 + 0) * STR;
    const float* wp1 = wB + (cq * 4 + 1) * STR;
    const float* wp2 = wB + (cq * 4 + 2) * STR;
    const float* wp3 = wB + (cq * 4 + 3) * STR;

    if (layer == 0) {
        for (int t = 0; t < SS; ++t) {
            const int slot = t & 3, eslot = (t - 1) & 3;
            if (tid == 0) {
                if (t >= 1) wait_ge(&c0[rg * 4 + eslot], 32u * (((unsigned)(t - 1) >> 2) + 1));
                if (t >= 4) wait_ge(&c1[rg * 4 + slot], 32u * ((unsigned)t >> 2)); // L1 done t-4
            }
            __syncthreads();
            // stage h0(t-1) rows (device-coherent) and x_t rows (cached)
            const float* hsrc = (t == 0) ? (hprev + row0 * HH)
                                         : (ring + eslot * (BB * HH) + row0 * HH);
            for (int i = tid; i < 16 * 256; i += 256) {      // 256 f2 per row (k=0..511)
                int rr = i >> 8, s = i & 255;
                float2 v = ld_coh2(hsrc + rr * HH + 2 * s);
                int k = 2 * s;
                *(float2*)&hAB[rr * STR + k + 4 * (k >> 8)] = v;
            }
            for (int i = tid; i < 16 * 64; i += 256) {       // 64 f4 per row (k=512..767)
                int rr = i >> 6, s = i & 63;
                float4 v = *(const float4*)(x + ((size_t)(row0 + rr) * SS + t) * II + 4 * s);
                *(float4*)&hAB[rr * STR + 512 + 4 * s + 8] = v;
            }
            __syncthreads();
            // compute: cols col0..col0+3, k in [kq*192, kq*192+192)
            float4 a0 = make_float4(0, 0, 0, 0), a1 = a0, a2 = a0, a3 = a0;
            #pragma unroll 4
            for (int i = 0; i < 48; ++i) {
                int k = kq * 192 + 4 * i;
                int a = k + 4 * (k >> 8);
                float4 h = *(const float4*)&hp[a];
                float4 w0 = *(const float4*)&wp0[a];
                a0.x = fmaf(h.x, w0.x, a0.x); a0.y = fmaf(h.y, w0.y, a0.y);
                a0.z = fmaf(h.z, w0.z, a0.z); a0.w = fmaf(h.w, w0.w, a0.w);
                float4 w1 = *(const float4*)&wp1[a];
                a1.x = fmaf(h.x, w1.x, a1.x); a1.y = fmaf(h.y, w1.y, a1.y);
                a1.z = fmaf(h.z, w1.z, a1.z); a1.w = fmaf(h.w, w1.w, a1.w);
                float4 w2 = *(const float4*)&wp2[a];
                a2.x = fmaf(h.x, w2.x, a2.x); a2.y = fmaf(h.y, w2.y, a2.y);
                a2.z = fmaf(h.z, w2.z, a2.z); a2.w = fmaf(h.w, w2.w, a2.w);
                float4 w3 = *(const float4*)&wp3[a];
                a3.x = fmaf(h.x, w3.x, a3.x); a3.y = fmaf(h.y, w3.y, a3.y);
                a3.z = fmaf(h.z, w3.z, a3.z); a3.w = fmaf(h.w, w3.w, a3.w);
            }
            float s0 = (a0.x + a0.y) + (a0.z + a0.w);
            float s1 = (a1.x + a1.y) + (a1.z + a1.w);
            float s2 = (a2.x + a2.y) + (a2.z + a2.w);
            float s3 = (a3.x + a3.y) + (a3.z + a3.w);
            s0 += __shfl_xor(s0, 1); s0 += __shfl_xor(s0, 2);
            s1 += __shfl_xor(s1, 1); s1 += __shfl_xor(s1, 2);
            s2 += __shfl_xor(s2, 1); s2 += __shfl_xor(s2, 2);
            s3 += __shfl_xor(s3, 1); s3 += __shfl_xor(s3, 2);
            if (kq == 0) {
                float o0 = tanhf(s0 + bias4.x), o1 = tanhf(s1 + bias4.y);
                float o2 = tanhf(s2 + bias4.z), o3 = tanhf(s3 + bias4.w);
                float* dst = ring + slot * (BB * HH) + (row0 + r) * HH + col0;
                st_coh2(dst, o0, o1); st_coh2(dst + 2, o2, o3);
            }
            __syncthreads();   // drains stores (compiler emits vmcnt(0) before barrier)
            if (tid == 0) add_flag(&c0[rg * 4 + slot]);
        }
    } else {
        for (int t = 0; t < SS; ++t) {
            const int slot = t & 3;
            if (tid == 0) {
                wait_ge(&c0[rg * 4 + slot], 32u * (((unsigned)t >> 2) + 1));       // h0(t) ready
                if (t >= 1) wait_ge(&c1[rg * 4 + ((t - 1) & 3)],
                                    32u * (((unsigned)(t - 1) >> 2) + 1));         // h1(t-1) ready
            }
            __syncthreads();
            const float* h0src = ring + slot * (BB * HH) + row0 * HH;
            const float* h1src = (t == 0) ? (hprev + BB * HH + row0 * HH)
                                          : (H1 + (size_t)(t - 1) * (BB * HH) + row0 * HH);
            for (int i = tid; i < 16 * 512; i += 256) {   // 512 f2 per row: 256 h0 + 256 h1
                int rr = i >> 9, s = i & 511;
                const float* src = (s < 256) ? (h0src + rr * HH + 2 * s)
                                             : (h1src + rr * HH + 2 * (s - 256));
                float2 v = ld_coh2(src);
                int k = 2 * s;
                *(float2*)&hAB[rr * STR + k + 4 * (k >> 8)] = v;
            }
            __syncthreads();
            float4 a0 = make_float4(0, 0, 0, 0), a1 = a0, a2 = a0, a3 = a0;
            #pragma unroll 4
            for (int i = 0; i < 64; ++i) {
                int k = kq * 256 + 4 * i;
                int a = k + 4 * (k >> 8);
                float4 h = *(const float4*)&hp[a];
                float4 w0 = *(const float4*)&wp0[a];
                a0.x = fmaf(h.x, w0.x, a0.x); a0.y = fmaf(h.y, w0.y, a0.y);
                a0.z = fmaf(h.z, w0.z, a0.z); a0.w = fmaf(h.w, w0.w, a0.w);
                float4 w1 = *(const float4*)&wp1[a];
                a1.x = fmaf(h.x, w1.x, a1.x); a1.y = fmaf(h.y, w1.y, a1.y);
                a1.z = fmaf(h.z, w1.z, a1.z); a1.w = fmaf(h.w, w1.w, a1.w);
                float4 w2 = *(const float4*)&wp2[a];
                a2.x = fmaf(h.x, w2.x, a2.x); a2.y = fmaf(h.y, w2.y, a2.y);
                a2.z = fmaf(h.z, w2.z, a2.z); a2.w = fmaf(h.w, w2.w, a2.w);
                float4 w3 = *(const float4*)&wp3[a];
                a3.x = fmaf(h.x, w3.x, a3.x); a3.y = fmaf(h.y, w3.y, a3.y);
                a3.z = fmaf(h.z, w3.z, a3.z); a3.w = fmaf(h.w, w3.w, a3.w);
            }
            float s0 = (a0.x + a0.y) + (a0.z + a0.w);
            float s1 = (a1.x + a1.y) + (a1.z + a1.w);
            float s2 = (a2.x + a2.y) + (a2.z + a2.w);
            float s3 = (a3.x + a3.y) + (a3.z + a3.w);
            s0 += __shfl_xor(s0, 1); s0 += __shfl_xor(s0, 2);
            s1 += __shfl_xor(s1, 1); s1 += __shfl_xor(s1, 2);
            s2 += __shfl_xor(s2, 1); s2 += __shfl_xor(s2, 2);
            s3 += __shfl_xor(s3, 1); s3 += __shfl_xor(s3, 2);
            if (kq == 0) {
                float o0 = tanhf(s0 + bias4.x), o1 = tanhf(s1 + bias4.y);
                float o2 = tanhf(s2 + bias4.z), o3 = tanhf(s3 + bias4.w);
                float* dst = H1 + (size_t)t * (BB * HH) + (row0 + r) * HH + col0;
                st_coh2(dst, o0, o1); st_coh2(dst + 2, o2, o3);
            }
            __syncthreads();
            if (tid == 0) add_flag(&c1[rg * 4 + slot]);
        }
    }
}

// ---------------- out GEMM: out[b][s][:] = H1[s][b][:] @ Wout + bout ----------------
__global__ __launch_bounds__(256) void out_k(
    const float* __restrict__ H1, const float* __restrict__ Wout,
    const float* __restrict__ bout, float* __restrict__ out)
{
    __shared__ float wchunk[32 * 256];
    __shared__ float htile[16 * 32];
    const int tid = threadIdx.x;
    const int r0 = blockIdx.x * 16;

    float acc[16];
    #pragma unroll
    for (int mm = 0; mm < 16; ++mm) acc[mm] = 0.f;

    for (int kc = 0; kc < HH; kc += 32) {
        for (int idx = tid; idx < 32 * 256; idx += 256)
            wchunk[idx] = Wout[(kc + (idx >> 8)) * OO + (idx & 255)];
        for (int idx = tid; idx < 16 * 32; idx += 256) {
            int mm = idx >> 5, kk = idx & 31;
            htile[idx] = H1[(size_t)(r0 + mm) * HH + kc + kk];
        }
        __syncthreads();
        for (int kk = 0; kk < 32; ++kk) {
            float w = wchunk[kk * 256 + tid];
            #pragma unroll
            for (int mm = 0; mm < 16; ++mm)
                acc[mm] = fmaf(htile[mm * 32 + kk], w, acc[mm]);
        }
        __syncthreads();
    }
    float bo = bout[tid];
    #pragma unroll
    for (int mm = 0; mm < 16; ++mm) {
        int rr = r0 + mm;
        int s = rr >> 6, b = rr & 63;
        out[((size_t)b * SS + s) * OO + tid] = acc[mm] + bo;
    }
}

// ---------------- final hidden states ----------------
__global__ __launch_bounds__(256) void tail_k(
    const float* __restrict__ ring, const float* __restrict__ H1,
    float* __restrict__ out_tail)
{
    int gid = blockIdx.x * 256 + threadIdx.x;
    if (gid < BB * HH)
        out_tail[gid] = ring[((SS - 1) & 3) * (BB * HH) + gid];
    else if (gid < 2 * BB * HH)
        out_tail[gid] = H1[(size_t)(SS - 1) * (BB * HH) + (gid - BB * HH)];
}

// ---------------- launch ----------------
extern "C" void kernel_launch(void* const* d_in, const int* in_sizes, int n_in,
                              void* d_out, int out_size, void* d_ws, size_t ws_size,
                              hipStream_t stream)
{
    const float* x     = (const float*)d_in[0];
    const float* hprev = (const float*)d_in[1];
    const float* Win   = (const float*)d_in[2];
    const float* bin   = (const float*)d_in[3];
    const float* Wi2h  = (const float*)d_in[4];
    const float* bi2h  = (const float*)d_in[5];
    const float* Wh2h  = (const float*)d_in[6];
    const float* bh2h  = (const float*)d_in[7];
    const float* Wout  = (const float*)d_in[8];
    const float* bout  = (const float*)d_in[9];

    float* ws   = (float*)d_ws;
    float* W0   = ws;
    float* b0   = W0 + (size_t)II * HH;
    float* ring = b0 + HH;
    float* H1   = ring + 4 * BB * HH;
    unsigned* cnt = (unsigned*)(H1 + (size_t)SS * BB * HH);
    unsigned* c0 = cnt;
    unsigned* c1 = cnt + 16;
    float* out  = (float*)d_out;

    hipMemsetAsync(cnt, 0, 32 * sizeof(unsigned), stream);
    fold_k<<<dim3((II * HH + HH + 255) / 256), dim3(256), 0, stream>>>(
        Win, bin, Wi2h, bi2h, bh2h, W0, b0);
    hipFuncSetAttribute((const void*)rnn_seq2,
                        hipFuncAttributeMaxDynamicSharedMemorySize, 132608);
    rnn_seq2<<<dim3(256), dim3(256), 132608, stream>>>(
        x, hprev, Wi2h, bi2h, Wh2h, bh2h, W0, b0, ring, H1, c0, c1);
    out_k<<<dim3((BB * SS) / 16), dim3(256), 0, stream>>>(H1, Wout, bout, out);
    tail_k<<<dim3((2 * BB * HH) / 256), dim3(256), 0, stream>>>(
        ring, H1, out + (size_t)BB * SS * OO);
}

// Round 3
// 5622.145 us; speedup vs baseline: 3.5651x; 1.7008x over previous
//
#include <hip/hip_runtime.h>
#include <math.h>

// CustomRNN: B=64,S=512,I=256,H=512,O=256,L=2 (fp32)
// R3 design: weights in REGISTERS (reused all 512 ticks), LDS only for h-tile
// staging + k-partial reduction. 256 persistent WGs (1/CU), no grid barrier.
//   L0 WGs (0..127):  h0(t) = tanh(h0(t-1)@Wh0 + x_t@W0 + b0)   [W0 = Win@Wi0 folded]
//   L1 WGs (128..255):h1(t) = tanh(h0(t)@Wi1 + h1(t-1)@Wh1 + b1)
// Tile: 8 rows x 32 cols per WG (8 row-groups x 16 col-groups per layer).
// Thread (kg=tid&31, cgrp=tid>>5): w4[NJ*4] float4 = 4 cols x k-slice
// {k = j*128 + kg*4 + e}. h-reads: ds_read_b128 at 16B-consecutive addrs across
// the half-wave -> conflict-free. k-partial reduction via LDS (stride 36).
// Cross-WG h exchange: per-access agent-scope relaxed atomics (sc1, MALL-coherent,
// no cache-wide fences). Sync: per-row-group monotonic counters, quorum 16,
// depth-4 h0 ring (L0 runs up to 3 ticks ahead).

constexpr int BB = 64;
constexpr int SS = 512;
constexpr int II = 256;
constexpr int HH = 512;
constexpr int OO = 256;
constexpr int BH = BB * HH;       // 32768
constexpr int RING_D = 4;
constexpr int STR0 = 772;         // 768 + 4 pad (L0: 512 h + 256 x)
constexpr int STR1 = 1028;        // 1024 + 4 pad (L1: 512 h0 + 512 h1)
constexpr int PSTR = 36;          // partial-slot stride (16B-aligned, bank-spread)
constexpr int HREG = 8 * STR1;    // 8224 floats
constexpr int PREG = 8 * 32 * PSTR; // 9216 floats
constexpr int LDS_BYTES = (HREG + PREG) * 4;  // 69760 B

#define SCOPE_AGENT __HIP_MEMORY_SCOPE_AGENT

__device__ __forceinline__ unsigned ld_flag(const unsigned* p) {
    return __hip_atomic_load((unsigned*)p, __ATOMIC_RELAXED, SCOPE_AGENT);
}
__device__ __forceinline__ void add_flag(unsigned* p) {
    __hip_atomic_fetch_add(p, 1u, __ATOMIC_RELAXED, SCOPE_AGENT);
}
__device__ __forceinline__ void wait_ge(const unsigned* p, unsigned target) {
    while (ld_flag(p) < target) __builtin_amdgcn_s_sleep(1);
}

union F2U { float2 f; unsigned long long u; };
__device__ __forceinline__ float2 ld_coh2(const float* p) {
    F2U v;
    v.u = __hip_atomic_load((unsigned long long*)p, __ATOMIC_RELAXED, SCOPE_AGENT);
    return v.f;
}
__device__ __forceinline__ void st_coh1(float* p, float a) {
    __hip_atomic_store(p, a, __ATOMIC_RELAXED, SCOPE_AGENT);
}

// ---------------- fold: W0 = Win@Wi0, b0 = bin@Wi0 + bi0 + bh0 ----------------
__global__ __launch_bounds__(256) void fold_k(
    const float* __restrict__ Win, const float* __restrict__ bin,
    const float* __restrict__ Wi2h, const float* __restrict__ bi2h,
    const float* __restrict__ bh2h,
    float* __restrict__ W0, float* __restrict__ b0)
{
    int gid = blockIdx.x * 256 + threadIdx.x;
    const float* Wi0 = Wi2h;
    if (gid < II * HH) {
        int i = gid / HH, j = gid % HH;
        float acc = 0.f;
        for (int k = 0; k < HH; ++k)
            acc = fmaf(Win[i * HH + k], Wi0[k * HH + j], acc);
        W0[gid] = acc;
    } else if (gid < II * HH + HH) {
        int j = gid - II * HH;
        float acc = bi2h[j] + bh2h[j];
        for (int k = 0; k < HH; ++k)
            acc = fmaf(bin[k], Wi0[k * HH + j], acc);
        b0[j] = acc;
    }
}

// ---------------- persistent sequential kernel ----------------
template <int LAYER>
__device__ __forceinline__ void rnn_body(
    const float* __restrict__ x, const float* __restrict__ hprev,
    const float* __restrict__ Wi2h, const float* __restrict__ bi2h,
    const float* __restrict__ Wh2h, const float* __restrict__ bh2h,
    const float* __restrict__ W0, const float* __restrict__ b0,
    float* __restrict__ ring, float* __restrict__ H1,
    unsigned* __restrict__ c0, unsigned* __restrict__ c1,
    float* hbuf, float* pbuf)
{
    constexpr int NJ  = LAYER ? 8 : 6;           // k-range = NJ*128
    constexpr int STR = LAYER ? STR1 : STR0;

    const int tid  = threadIdx.x;
    const int id   = blockIdx.x & 127;
    const int rg   = id >> 4;        // 0..7  (8 rows each)
    const int cg   = id & 15;        // 0..15 (32 cols each)
    const int row0 = rg * 8;
    const int col0 = cg * 32;
    const int kg   = tid & 31;       // k-group within half-wave
    const int cgrp = (tid >> 5) & 7; // 8 col-groups of 4
    const int cbase = col0 + cgrp * 4;

    // ---- weight slice -> registers (lives all 512 ticks) ----
    float4 w4[NJ * 4];
    #pragma unroll
    for (int j = 0; j < NJ; ++j) {
        #pragma unroll
        for (int e = 0; e < 4; ++e) {
            int k = j * 128 + kg * 4 + e;
            const float* src;
            if (LAYER == 0)
                src = (k < 512) ? (Wh2h + (size_t)k * HH + cbase)
                                : (W0 + (size_t)(k - 512) * HH + cbase);
            else
                src = (k < 512) ? (Wi2h + (size_t)HH * HH + (size_t)k * HH + cbase)
                                : (Wh2h + (size_t)HH * HH + (size_t)(k - 512) * HH + cbase);
            w4[j * 4 + e] = *(const float4*)src;
        }
    }

    float bias_red;
    {
        int c = col0 + (tid & 31);
        bias_red = LAYER ? (bi2h[HH + c] + bh2h[HH + c]) : b0[c];
    }

    for (int t = 0; t < SS; ++t) {
        if (tid == 0) {
            if (LAYER == 0) {
                if (t >= 1) wait_ge(c0 + rg, 16u * (unsigned)t);                 // h0(t-1) ready
                if (t >= RING_D) wait_ge(c1 + rg, 16u * (unsigned)(t - RING_D + 1)); // slot free
            } else {
                wait_ge(c0 + rg, 16u * (unsigned)(t + 1));                       // h0(t) ready
                if (t >= 1) wait_ge(c1 + rg, 16u * (unsigned)t);                 // h1(t-1) ready
            }
        }
        __syncthreads();

        // ---- stage h (+x) into LDS: loads first (pipelined), writes after ----
        if (LAYER == 0) {
            const float* hsrc = (t == 0)
                ? (hprev + (size_t)row0 * HH)
                : (ring + (size_t)((t - 1) & (RING_D - 1)) * BH + (size_t)row0 * HH);
            float2 tmp[8];
            #pragma unroll
            for (int u = 0; u < 8; ++u) tmp[u] = ld_coh2(hsrc + u * HH + 2 * tid);
            float4 xv[2];
            #pragma unroll
            for (int v = 0; v < 2; ++v) {
                int rr = 4 * v + (tid >> 6);
                xv[v] = *(const float4*)(x + ((size_t)(row0 + rr) * SS + t) * II + 4 * (tid & 63));
            }
            #pragma unroll
            for (int u = 0; u < 8; ++u) *(float2*)&hbuf[u * STR + 2 * tid] = tmp[u];
            #pragma unroll
            for (int v = 0; v < 2; ++v) {
                int rr = 4 * v + (tid >> 6);
                *(float4*)&hbuf[rr * STR + 512 + 4 * (tid & 63)] = xv[v];
            }
        } else {
            const float* h0src = ring + (size_t)(t & (RING_D - 1)) * BH + (size_t)row0 * HH;
            const float* h1src = (t == 0)
                ? (hprev + BH + (size_t)row0 * HH)
                : (H1 + (size_t)(t - 1) * BH + (size_t)row0 * HH);
            float2 ta[8], tb[8];
            #pragma unroll
            for (int u = 0; u < 8; ++u) ta[u] = ld_coh2(h0src + u * HH + 2 * tid);
            #pragma unroll
            for (int u = 0; u < 8; ++u) tb[u] = ld_coh2(h1src + u * HH + 2 * tid);
            #pragma unroll
            for (int u = 0; u < 8; ++u) *(float2*)&hbuf[u * STR + 2 * tid] = ta[u];
            #pragma unroll
            for (int u = 0; u < 8; ++u) *(float2*)&hbuf[u * STR + 512 + 2 * tid] = tb[u];
        }
        __syncthreads();

        // ---- FMA: acc[r] (4 cols) over this thread's k-slice ----
        float4 acc[8];
        #pragma unroll
        for (int r = 0; r < 8; ++r) acc[r] = make_float4(0.f, 0.f, 0.f, 0.f);
        #pragma unroll
        for (int r = 0; r < 8; ++r) {
            #pragma unroll
            for (int j = 0; j < NJ; ++j) {
                float4 h4 = *(const float4*)&hbuf[r * STR + j * 128 + kg * 4];
                float4 wa = w4[j * 4 + 0];
                float4 wb = w4[j * 4 + 1];
                float4 wc = w4[j * 4 + 2];
                float4 wd = w4[j * 4 + 3];
                acc[r].x = fmaf(h4.x, wa.x, acc[r].x);
                acc[r].y = fmaf(h4.x, wa.y, acc[r].y);
                acc[r].z = fmaf(h4.x, wa.z, acc[r].z);
                acc[r].w = fmaf(h4.x, wa.w, acc[r].w);
                acc[r].x = fmaf(h4.y, wb.x, acc[r].x);
                acc[r].y = fmaf(h4.y, wb.y, acc[r].y);
                acc[r].z = fmaf(h4.y, wb.z, acc[r].z);
                acc[r].w = fmaf(h4.y, wb.w, acc[r].w);
                acc[r].x = fmaf(h4.z, wc.x, acc[r].x);
                acc[r].y = fmaf(h4.z, wc.y, acc[r].y);
                acc[r].z = fmaf(h4.z, wc.z, acc[r].z);
                acc[r].w = fmaf(h4.z, wc.w, acc[r].w);
                acc[r].x = fmaf(h4.w, wd.x, acc[r].x);
                acc[r].y = fmaf(h4.w, wd.y, acc[r].y);
                acc[r].z = fmaf(h4.w, wd.z, acc[r].z);
                acc[r].w = fmaf(h4.w, wd.w, acc[r].w);
            }
        }

        // ---- reduce k-partials across the 32 kg lanes via LDS transpose ----
        #pragma unroll
        for (int r = 0; r < 8; ++r) {
            pbuf[(r * 32 + cgrp * 4 + 0) * PSTR + kg] = acc[r].x;
            pbuf[(r * 32 + cgrp * 4 + 1) * PSTR + kg] = acc[r].y;
            pbuf[(r * 32 + cgrp * 4 + 2) * PSTR + kg] = acc[r].z;
            pbuf[(r * 32 + cgrp * 4 + 3) * PSTR + kg] = acc[r].w;
        }
        __syncthreads();
        {
            int rr = tid >> 5, cl = tid & 31;
            float s = 0.f;
            #pragma unroll
            for (int j2 = 0; j2 < 8; ++j2) {
                float4 v = *(const float4*)&pbuf[(rr * 32 + cl) * PSTR + 4 * j2];
                s += (v.x + v.y) + (v.z + v.w);
            }
            float o = tanhf(s + bias_red);
            float* dst = LAYER
                ? (H1 + (size_t)t * BH + (size_t)(row0 + rr) * HH + col0 + cl)
                : (ring + (size_t)(t & (RING_D - 1)) * BH + (size_t)(row0 + rr) * HH + col0 + cl);
            st_coh1(dst, o);
        }
        __syncthreads();   // drains each wave's stores (vmcnt(0)) before flag
        if (tid == 0) add_flag((LAYER ? c1 : c0) + rg);
    }
}

__global__ __launch_bounds__(256, 1) void rnn_seq3(
    const float* __restrict__ x, const float* __restrict__ hprev,
    const float* __restrict__ Wi2h, const float* __restrict__ bi2h,
    const float* __restrict__ Wh2h, const float* __restrict__ bh2h,
    const float* __restrict__ W0, const float* __restrict__ b0,
    float* __restrict__ ring, float* __restrict__ H1,
    unsigned* __restrict__ c0, unsigned* __restrict__ c1)
{
    extern __shared__ float lds[];
    float* hbuf = lds;
    float* pbuf = lds + HREG;
    if (blockIdx.x >> 7)
        rnn_body<1>(x, hprev, Wi2h, bi2h, Wh2h, bh2h, W0, b0, ring, H1, c0, c1, hbuf, pbuf);
    else
        rnn_body<0>(x, hprev, Wi2h, bi2h, Wh2h, bh2h, W0, b0, ring, H1, c0, c1, hbuf, pbuf);
}

// ---------------- out GEMM: out[b][s][:] = H1[s][b][:] @ Wout + bout ----------------
__global__ __launch_bounds__(256) void out_k(
    const float* __restrict__ H1, const float* __restrict__ Wout,
    const float* __restrict__ bout, float* __restrict__ out)
{
    __shared__ float wchunk[32 * 256];
    __shared__ float htile[16 * 32];
    const int tid = threadIdx.x;
    const int r0 = blockIdx.x * 16;

    float acc[16];
    #pragma unroll
    for (int mm = 0; mm < 16; ++mm) acc[mm] = 0.f;

    for (int kc = 0; kc < HH; kc += 32) {
        for (int idx = tid; idx < 32 * 256; idx += 256)
            wchunk[idx] = Wout[(kc + (idx >> 8)) * OO + (idx & 255)];
        for (int idx = tid; idx < 16 * 32; idx += 256) {
            int mm = idx >> 5, kk = idx & 31;
            htile[idx] = H1[(size_t)(r0 + mm) * HH + kc + kk];
        }
        __syncthreads();
        for (int kk = 0; kk < 32; ++kk) {
            float w = wchunk[kk * 256 + tid];
            #pragma unroll
            for (int mm = 0; mm < 16; ++mm)
                acc[mm] = fmaf(htile[mm * 32 + kk], w, acc[mm]);
        }
        __syncthreads();
    }
    float bo = bout[tid];
    #pragma unroll
    for (int mm = 0; mm < 16; ++mm) {
        int rr = r0 + mm;
        int s = rr >> 6, b = rr & 63;
        out[((size_t)b * SS + s) * OO + tid] = acc[mm] + bo;
    }
}

// ---------------- final hidden states ----------------
__global__ __launch_bounds__(256) void tail_k(
    const float* __restrict__ ring, const float* __restrict__ H1,
    float* __restrict__ out_tail)
{
    int gid = blockIdx.x * 256 + threadIdx.x;
    if (gid < BB * HH)
        out_tail[gid] = ring[((SS - 1) & (RING_D - 1)) * BH + gid];
    else if (gid < 2 * BB * HH)
        out_tail[gid] = H1[(size_t)(SS - 1) * BH + (gid - BB * HH)];
}

// ---------------- launch ----------------
extern "C" void kernel_launch(void* const* d_in, const int* in_sizes, int n_in,
                              void* d_out, int out_size, void* d_ws, size_t ws_size,
                              hipStream_t stream)
{
    const float* x     = (const float*)d_in[0];
    const float* hprev = (const float*)d_in[1];
    const float* Win   = (const float*)d_in[2];
    const float* bin   = (const float*)d_in[3];
    const float* Wi2h  = (const float*)d_in[4];
    const float* bi2h  = (const float*)d_in[5];
    const float* Wh2h  = (const float*)d_in[6];
    const float* bh2h  = (const float*)d_in[7];
    const float* Wout  = (const float*)d_in[8];
    const float* bout  = (const float*)d_in[9];

    float* ws   = (float*)d_ws;
    float* W0   = ws;
    float* b0   = W0 + (size_t)II * HH;
    float* ring = b0 + HH;
    float* H1   = ring + (size_t)RING_D * BH;
    unsigned* cnt = (unsigned*)(H1 + (size_t)SS * BH);
    unsigned* c0 = cnt;
    unsigned* c1 = cnt + 8;
    float* out  = (float*)d_out;

    hipMemsetAsync(cnt, 0, 16 * sizeof(unsigned), stream);
    fold_k<<<dim3((II * HH + HH + 255) / 256), dim3(256), 0, stream>>>(
        Win, bin, Wi2h, bi2h, bh2h, W0, b0);
    hipFuncSetAttribute((const void*)rnn_seq3,
                        hipFuncAttributeMaxDynamicSharedMemorySize, LDS_BYTES);
    rnn_seq3<<<dim3(256), dim3(256), LDS_BYTES, stream>>>(
        x, hprev, Wi2h, bi2h, Wh2h, bh2h, W0, b0, ring, H1, c0, c1);
    out_k<<<dim3((BB * SS) / 16), dim3(256), 0, stream>>>(H1, Wout, bout, out);
    tail_k<<<dim3((2 * BB * HH) / 256), dim3(256), 0, stream>>>(
        ring, H1, out + (size_t)BB * SS * OO);
}